// Round 2
// baseline (329.969 us; speedup 1.0000x reference)
//
#include <hip/hip_runtime.h>
#include <hip/hip_bf16.h>

typedef unsigned short u16;
typedef __bf16 bf16x8_t __attribute__((ext_vector_type(8)));
typedef __bf16 bf16x4_t __attribute__((ext_vector_type(4)));
typedef float fx4 __attribute__((ext_vector_type(4)));
typedef u16 u16x8_t __attribute__((ext_vector_type(8)));
typedef u16 u16x4_t __attribute__((ext_vector_type(4)));

#define SCALE_Q 0.17677669529663687f
#define PSTR 328   // P/VT LDS row stride in bf16 elems: 656B, 16B-aligned, breaks pow2 conflicts

__device__ __forceinline__ u16 f2bu(float f) {
  __bf16 h = (__bf16)f;
  return __builtin_bit_cast(u16, h);
}

#define GLD16(gp, lp) __builtin_amdgcn_global_load_lds( \
    (const __attribute__((address_space(1))) void*)(gp), \
    (__attribute__((address_space(3))) void*)(lp), 16, 0, 0)

// ---------------- prep: x permute + convert to bf16 [75264][256] ----------------
__global__ void prep_x(const float* __restrict__ x, u16* __restrict__ xw) {
  int t = blockIdx.x * 256 + threadIdx.x;      // 75264*32 threads, 8 elems each
  int m = t >> 5, c8 = (t & 31) * 8;
  int b = m / 294, n = m % 294;
  int hx = b >> 4, wy = b & 15;
  int l = n / 49, rem = n % 49;
  int w1 = rem / 7, w2 = rem % 7;
  size_t xoff = (((((size_t)l * 16 + hx) * 16 + wy) * 7 + w1) * 7 + w2) * 256 + c8;
  const float4* src = (const float4*)(x + xoff);
  float4 v0 = src[0], v1 = src[1];
  u16x8_t o;
  o[0] = f2bu(v0.x); o[1] = f2bu(v0.y); o[2] = f2bu(v0.z); o[3] = f2bu(v0.w);
  o[4] = f2bu(v1.x); o[5] = f2bu(v1.y); o[6] = f2bu(v1.z); o[7] = f2bu(v1.w);
  *(u16x8_t*)(xw + (size_t)m * 256 + c8) = o;
}

// ---------------- prep: weights -> bf16 (fold softmax SCALE into q-rows) -------
__global__ void prep_w(const float* __restrict__ wqkv, const float* __restrict__ wout,
                       u16* __restrict__ bqkv, u16* __restrict__ bwout) {
  int t = blockIdx.x * 256 + threadIdx.x;      // 262144 threads
  if (t < 196608) {
    float v = wqkv[t];
    if (t < 65536) v *= SCALE_Q;               // rows 0..255 are Q rows
    bqkv[t] = f2bu(v);
  } else {
    int i = t - 196608;
    bwout[i] = f2bu(wout[i]);
  }
}

// ---------------- prep: bias in MFMA C-fragment layout [h][s][t][lane][4] ------
__global__ void prep_bias(const float* __restrict__ table, u16* __restrict__ bias_pre) {
  int t = blockIdx.x * 256 + threadIdx.x;      // 8*19*20*64 = 194560 threads
  int lane = t & 63;
  int rest = t >> 6;
  int ct = rest % 20; rest /= 20;
  int s = rest % 19; int h = rest / 19;
  int col = ct * 16 + (lane & 15);
  int rbase = s * 16 + ((lane >> 4) << 2);
  u16x4_t o;
#pragma unroll
  for (int r = 0; r < 4; ++r) {
    float v;
    if (col >= 294) {
      v = -1e30f;                              // mask padded key columns
    } else {
      int i = rbase + r; if (i > 293) i = 293; // padded query rows: clamp (values unused)
      int l1 = i / 49, r1 = i % 49, a1 = r1 / 7, b1 = r1 % 7;
      int l2 = col / 49, r2 = col % 49, a2 = r2 / 7, b2 = r2 % 7;
      int idx = (l1 - l2 + 5) * 169 + (a1 - a2 + 6) * 13 + (b1 - b2 + 6);
      v = table[idx * 8 + h];
    }
    o[r] = f2bu(v);
  }
  *(u16x4_t*)(bias_pre + (size_t)t * 4) = o;
}

// ---------------- 128x128x32 bf16 MFMA GEMM (B^T layout: out = A @ B^T) --------
// EPI 0: C bf16 [75264][768] (qkv).  EPI 1: C fp32 scattered to output layout.
template <int EPI>
__global__ __launch_bounds__(256, 2) void gemm128(const u16* __restrict__ A,
                                                  const u16* __restrict__ Bw,
                                                  u16* __restrict__ Cb,
                                                  float* __restrict__ Cf) {
  __shared__ u16 sA[128 * 32];
  __shared__ u16 sB[128 * 32];
  const int tid = threadIdx.x, lane = tid & 63, wave = tid >> 6;
  const int wr = wave >> 1, wc = wave & 1;
  const int tm = blockIdx.x, tn = blockIdx.y;
  fx4 acc[4][4] = {};
#pragma unroll 1
  for (int kt = 0; kt < 8; ++kt) {
    __syncthreads();
#pragma unroll
    for (int rnd = 0; rnd < 2; ++rnd) {
      int o = rnd * 4096 + tid * 16;           // LDS byte offset; lane*16 pattern
      int row = o >> 6, cb = o & 63;
      const u16* gA = A + (size_t)(tm * 128 + row) * 256 + kt * 32 + (cb >> 1);
      const u16* gB = Bw + (size_t)(tn * 128 + row) * 256 + kt * 32 + (cb >> 1);
      GLD16(gA, (char*)sA + o);
      GLD16(gB, (char*)sB + o);
    }
    __syncthreads();
    bf16x8_t af[4], bfr[4];
#pragma unroll
    for (int i = 0; i < 4; ++i)
      af[i] = *(const bf16x8_t*)&sA[(wr * 64 + i * 16 + (lane & 15)) * 32 + (lane >> 4) * 8];
#pragma unroll
    for (int j = 0; j < 4; ++j)
      bfr[j] = *(const bf16x8_t*)&sB[(wc * 64 + j * 16 + (lane & 15)) * 32 + (lane >> 4) * 8];
#pragma unroll
    for (int i = 0; i < 4; ++i)
#pragma unroll
      for (int j = 0; j < 4; ++j)
        acc[i][j] = __builtin_amdgcn_mfma_f32_16x16x32_bf16(af[i], bfr[j], acc[i][j], 0, 0, 0);
  }
  const int r0 = tm * 128 + wr * 64, c0 = tn * 128 + wc * 64;
#pragma unroll
  for (int i = 0; i < 4; ++i) {
#pragma unroll
    for (int j = 0; j < 4; ++j) {
#pragma unroll
      for (int r = 0; r < 4; ++r) {
        int row = r0 + i * 16 + (lane >> 4) * 4 + r;
        int col = c0 + j * 16 + (lane & 15);
        float v = acc[i][j][r];
        if (EPI == 0) {
          Cb[(size_t)row * 768 + col] = f2bu(v);
        } else {
          int b = row / 294, n = row % 294;
          int hx = b >> 4, wy = b & 15;
          int l = n / 49, rem = n % 49, w1 = rem / 7, w2 = rem % 7;
          size_t off = (((((size_t)l * 16 + hx) * 16 + wy) * 7 + w1) * 7 + w2) * 256 + col;
          Cf[off] = v;
        }
      }
    }
  }
}

// ---------------- fused attention: one block per (window, head) ----------------
// qkv layout [256][294][768]: cols 0-255 Q(scaled), 256-511 K, 512-767 V.
__global__ __launch_bounds__(256, 2) void attn(const u16* __restrict__ qkv,
                                               const u16* __restrict__ bias_pre,
                                               u16* __restrict__ aout) {
  __shared__ u16 VT[32 * PSTR];                // V transposed: [dh 32][tok 320+pad]
  __shared__ u16 P[4][16 * PSTR];              // per-wave P strip [16][320+pad]
  const int blk = blockIdx.x;
  const int b = blk >> 3, h = blk & 7;
  const int tid = threadIdx.x, lane = tid & 63, wave = tid >> 6;
  const size_t base = (size_t)b * 294 * 768;

  // build V^T in LDS (zero-fill padded tokens 294..319)
  for (int i = tid; i < 320 * 4; i += 256) {
    int tok = i >> 2, c8 = (i & 3) * 8;
    if (tok < 294) {
      u16x8_t v = *(const u16x8_t*)(qkv + base + (size_t)tok * 768 + 512 + h * 32 + c8);
#pragma unroll
      for (int j = 0; j < 8; ++j) VT[(c8 + j) * PSTR + tok] = v[j];
    } else {
#pragma unroll
      for (int j = 0; j < 8; ++j) VT[(c8 + j) * PSTR + tok] = 0;
    }
  }
  __syncthreads();

  u16* Pw = P[wave];
  for (int s = wave; s < 19; s += 4) {
    // Q A-fragment straight from global: row = lane&15, k = (lane>>4)*8
    int qr = s * 16 + (lane & 15); if (qr > 293) qr = 293;
    bf16x8_t qf = *(const bf16x8_t*)(qkv + base + (size_t)qr * 768 + h * 32 + (lane >> 4) * 8);

    // accumulators init = bias fragment (includes -1e30 column mask)
    fx4 acc[20];
    const u16* bp = bias_pre + ((size_t)((h * 19 + s) * 20) * 64 + lane) * 4;
#pragma unroll
    for (int t = 0; t < 20; ++t) {
      bf16x4_t bv = *(const bf16x4_t*)(bp + t * 256);
      fx4 a; a[0] = (float)bv[0]; a[1] = (float)bv[1]; a[2] = (float)bv[2]; a[3] = (float)bv[3];
      acc[t] = a;
    }
    // S = Q K^T + bias
#pragma unroll
    for (int t = 0; t < 20; ++t) {
      int kr = t * 16 + (lane & 15); if (kr > 293) kr = 293;
      bf16x8_t kf = *(const bf16x8_t*)(qkv + base + (size_t)kr * 768 + 256 + h * 32 + (lane >> 4) * 8);
      acc[t] = __builtin_amdgcn_mfma_f32_16x16x32_bf16(qf, kf, acc[t], 0, 0, 0);
    }
    // wave-parallel softmax over 320 cols (rows live in groups of 16 lanes)
    float m[4], sum[4];
#pragma unroll
    for (int r = 0; r < 4; ++r) {
      float mv = acc[0][r];
#pragma unroll
      for (int t = 1; t < 20; ++t) mv = fmaxf(mv, acc[t][r]);
      mv = fmaxf(mv, __shfl_xor(mv, 1));
      mv = fmaxf(mv, __shfl_xor(mv, 2));
      mv = fmaxf(mv, __shfl_xor(mv, 4));
      mv = fmaxf(mv, __shfl_xor(mv, 8));
      m[r] = mv;
    }
#pragma unroll
    for (int r = 0; r < 4; ++r) {
      float sv = 0.f;
#pragma unroll
      for (int t = 0; t < 20; ++t) {
        float e = __expf(acc[t][r] - m[r]);
        acc[t][r] = e;
        sv += e;
      }
      sv += __shfl_xor(sv, 1);
      sv += __shfl_xor(sv, 2);
      sv += __shfl_xor(sv, 4);
      sv += __shfl_xor(sv, 8);
      sum[r] = sv;
    }
    // P -> LDS (bf16), C-layout scatter
    const int prow0 = (lane >> 4) * 4;
#pragma unroll
    for (int t = 0; t < 20; ++t) {
      int pc = t * 16 + (lane & 15);
#pragma unroll
      for (int r = 0; r < 4; ++r) Pw[(prow0 + r) * PSTR + pc] = f2bu(acc[t][r]);
    }
    // O = P V   (A-frag from P LDS, B-frag from V^T LDS)
    fx4 o0 = {}, o1 = {};
#pragma unroll
    for (int kt = 0; kt < 10; ++kt) {
      bf16x8_t pf = *(const bf16x8_t*)&Pw[(lane & 15) * PSTR + kt * 32 + (lane >> 4) * 8];
      bf16x8_t v0 = *(const bf16x8_t*)&VT[(lane & 15) * PSTR + kt * 32 + (lane >> 4) * 8];
      bf16x8_t v1 = *(const bf16x8_t*)&VT[(16 + (lane & 15)) * PSTR + kt * 32 + (lane >> 4) * 8];
      o0 = __builtin_amdgcn_mfma_f32_16x16x32_bf16(pf, v0, o0, 0, 0, 0);
      o1 = __builtin_amdgcn_mfma_f32_16x16x32_bf16(pf, v1, o1, 0, 0, 0);
    }
    // normalize + store attn output bf16 [75264][256]
#pragma unroll
    for (int r = 0; r < 4; ++r) {
      int n = s * 16 + prow0 + r;
      if (n < 294) {
        float inv = 1.0f / sum[r];
        size_t ro = ((size_t)b * 294 + n) * 256 + h * 32;
        aout[ro + (lane & 15)] = f2bu(o0[r] * inv);
        aout[ro + 16 + (lane & 15)] = f2bu(o1[r] * inv);
      }
    }
  }
}

extern "C" void kernel_launch(void* const* d_in, const int* in_sizes, int n_in,
                              void* d_out, int out_size, void* d_ws, size_t ws_size,
                              hipStream_t stream) {
  (void)in_sizes; (void)n_in; (void)out_size; (void)ws_size;
  const float* x    = (const float*)d_in[0];
  const float* wqkv = (const float*)d_in[1];
  const float* wout = (const float*)d_in[2];
  const float* btab = (const float*)d_in[3];
  float* out = (float*)d_out;
  char* ws = (char*)d_ws;
  u16* xw    = (u16*)(ws);                     // 75264*256*2   = 38,535,168
  u16* bqkv  = (u16*)(ws + 38535168);          // 768*256*2     =    393,216
  u16* bwout = (u16*)(ws + 38928384);          // 256*256*2     =    131,072
  u16* biasp = (u16*)(ws + 39059456);          // 194560*4*2    =  1,556,480
  u16* qkv   = (u16*)(ws + 40615936);          // 75264*768*2   = 115,605,504 (tot ~149MB)
  u16* aout  = xw;                             // reuse: xw dead after gemm<0>

  prep_x<<<9408, 256, 0, stream>>>(x, xw);
  prep_w<<<1024, 256, 0, stream>>>(wqkv, wout, bqkv, bwout);
  prep_bias<<<760, 256, 0, stream>>>(btab, biasp);
  gemm128<0><<<dim3(588, 6), 256, 0, stream>>>(xw, bqkv, qkv, nullptr);
  attn<<<2048, 256, 0, stream>>>(qkv, biasp, aout);
  gemm128<1><<<dim3(588, 2), 256, 0, stream>>>(aout, bwout, nullptr, out);
}